// Round 7
// baseline (403.635 us; speedup 1.0000x reference)
//
#include <hip/hip_runtime.h>
#include <hip/hip_bf16.h>
#include <cstddef>
#include <cstdint>

// ---------------- problem constants ----------------
#define M_TOK   16384      // 32*512 tokens
#define N_CODE  8192       // NUM_LATENTS
#define K_DIM   256        // LATENT_DIM
#define NSPLIT  16         // R12: 2048 short blocks -> dynamic packing at 3 blocks/CU.
                           // XCD x hosts splits {x, x+8}: 2 x 512KB W slices, L2-resident.
#define BM      128
#define BN      128
#define BK      32         // 34 KB LDS/block -> 3 blocks/CU fit (102 KB < 160)
#define KSTEPS  (K_DIM / BK)                 // 8
#define TILES   ((N_CODE / NSPLIT) / BN)     // 4

// R12 (session synthesis): R5 skeleton at THREE blocks/CU — the untested occupancy
// bucket. R5: 45% MfmaUtil = MFMA/(MFMA+LDS) serialization within a block; only
// cross-block overlap helps (R6/R7/R8 intra-block attempts all regressed).
// R10 (4 blk/CU) died of spill: 128-reg bucket vs ~180-reg live set. 3 waves/SIMD
// needs unified <=170: live set 180 - x2r[16] (moved to epilogue, R9-validated)
// ~= 164. launch_bounds(256,3) requests exactly that. Arithmetic at BK=32:
// MFMA 931 cyc vs LDS 1024 cyc per block-step -> 3 independent schedules should
// lift MfmaUtil toward ~60%. Failure signature to check: WRITE_SIZE >> 2MB = spill.
// Accumulation: ascending K=32 slices, same MFMA triple -> bit-exact (R10-proven).

typedef short bf16x8 __attribute__((ext_vector_type(8)));  // 8 bf16 = 4 VGPRs
typedef float f32x4  __attribute__((ext_vector_type(4)));

__device__ __forceinline__ unsigned short f2bf_rne(float f) {
    unsigned u = __float_as_uint(f);
    unsigned r = u + 0x7FFFu + ((u >> 16) & 1u);
    return (unsigned short)(r >> 16);
}
__device__ __forceinline__ float bf2f(unsigned short h) {
    union { unsigned u; float f; } c; c.u = ((unsigned)h) << 16; return c.f;
}

__device__ __forceinline__ void gload16(const void* g, void* l) {
    __builtin_amdgcn_global_load_lds(
        (const __attribute__((address_space(1))) void*)g,
        (__attribute__((address_space(3))) void*)l, 16, 0, 0);
}

// ---------------- prep: bf16 hi/lo split + fp32 norms ----------------
__global__ void vq_prep(const float* __restrict__ x, const float* __restrict__ cb,
                        unsigned short* __restrict__ xh, unsigned short* __restrict__ xl,
                        unsigned short* __restrict__ wh, unsigned short* __restrict__ wl,
                        float* __restrict__ x2, float* __restrict__ w2) {
    int gt   = blockIdx.x * blockDim.x + threadIdx.x;
    int row  = gt >> 6;
    int lane = gt & 63;
    if (row >= M_TOK + N_CODE) return;
    const float* src; unsigned short *dh, *dl; float* dn;
    if (row < M_TOK) {
        src = x + (size_t)row * K_DIM;
        dh = xh + (size_t)row * K_DIM; dl = xl + (size_t)row * K_DIM; dn = x2 + row;
    } else {
        int r = row - M_TOK;
        src = cb + (size_t)r * K_DIM;
        dh = wh + (size_t)r * K_DIM; dl = wl + (size_t)r * K_DIM; dn = w2 + r;
    }
    float4 v = ((const float4*)src)[lane];
    unsigned short h0 = f2bf_rne(v.x), h1 = f2bf_rne(v.y);
    unsigned short h2 = f2bf_rne(v.z), h3 = f2bf_rne(v.w);
    unsigned short l0 = f2bf_rne(v.x - bf2f(h0)), l1 = f2bf_rne(v.y - bf2f(h1));
    unsigned short l2 = f2bf_rne(v.z - bf2f(h2)), l3 = f2bf_rne(v.w - bf2f(h3));
    ushort4 hv; hv.x = h0; hv.y = h1; hv.z = h2; hv.w = h3;
    ushort4 lv; lv.x = l0; lv.y = l1; lv.z = l2; lv.w = l3;
    ((ushort4*)dh)[lane] = hv;
    ((ushort4*)dl)[lane] = lv;
    float s = v.x*v.x + v.y*v.y + v.z*v.z + v.w*v.w;
    #pragma unroll
    for (int off = 32; off > 0; off >>= 1) s += __shfl_down(s, off);
    if (lane == 0) *dn = s;
}

// ---------------- main: R5 skeleton, BK=32, 3 blocks/CU ----------------
// Swizzle (R10-proven bit-exact, 0 conflicts): LDS slot s of row r holds global chunk
// s ^ ((r>>1)&3); staging lane fetches chunk (lane&3)^((lane>>3)&3); read slot
// quad ^ ((l15>>1)&3).
__global__ __launch_bounds__(256, 3)
void vq_main_mfma(const unsigned short* __restrict__ xh, const unsigned short* __restrict__ xl,
                  const unsigned short* __restrict__ wh, const unsigned short* __restrict__ wl,
                  const float* __restrict__ x2, const float* __restrict__ w2,
                  float* __restrict__ pminv, int* __restrict__ pmini) {
    // [128 rows][32 bf16] = 64 B rows; 8 KB per array, 32 KB total
    __shared__ unsigned short xh_s[BM][BK];
    __shared__ unsigned short xl_s[BM][BK];
    __shared__ unsigned short wh_s[BN][BK];
    __shared__ unsigned short wl_s[BN][BK];
    __shared__ float red_d[BM][2];
    __shared__ int   red_i[BM][2];

    const int split = blockIdx.x;            // 0..15
    const int mtile = blockIdx.y;            // 0..127
    const int gm    = mtile * BM;
    const int tid   = threadIdx.x;
    const int w     = tid >> 6;              // wave 0..3
    const int lane  = tid & 63;
    const int wr    = w >> 1;                // row half (0/1)
    const int wc    = w & 1;                 // col half (0/1)
    const int quad  = lane >> 4;             // 0..3
    const int l15   = lane & 15;

    // staging: wave w covers rows [w*32, w*32+32) of each array, 2 instrs of 16 rows.
    const int w32   = w * 32;
    const int srow4 = lane >> 2;                       // 0..15
    const int sg    = (lane & 3) ^ ((lane >> 3) & 3);  // pre-swizzled global chunk

    float minv[16];
    int   mini[16];
    #pragma unroll
    for (int i = 0; i < 16; ++i) { minv[i] = 3.4e38f; mini[i] = 0; }

    const char* xhp = (const char*)xh;
    const char* xlp = (const char*)xl;
    const char* whp = (const char*)wh;
    const char* wlp = (const char*)wl;

    const int sl = quad ^ ((l15 >> 1) & 3);    // swizzled read slot (0..3)

    for (int tile = 0; tile < TILES; ++tile) {
        const int nb = split * (N_CODE / NSPLIT) + tile * BN;

        f32x4 acc[4][4];
        #pragma unroll
        for (int rt = 0; rt < 4; ++rt)
            #pragma unroll
            for (int ct = 0; ct < 4; ++ct)
                acc[rt][ct] = (f32x4){0.f, 0.f, 0.f, 0.f};

        for (int kc = 0; kc < KSTEPS; ++kc) {
            __syncthreads();     // protect LDS from previous iteration's readers
            #pragma unroll
            for (int i = 0; i < 2; ++i) {
                int rowl = w32 + i * 16 + srow4;     // tile row this lane fetches
                size_t xoff = (size_t)(gm + rowl) * (K_DIM*2) + (size_t)kc*(BK*2) + (size_t)sg*16;
                size_t woff = (size_t)(nb + rowl) * (K_DIM*2) + (size_t)kc*(BK*2) + (size_t)sg*16;
                unsigned ldso = (unsigned)w32 * (BK*2) + i * 1024;   // wave-uniform
                gload16(xhp + xoff, (char*)&xh_s[0][0] + ldso);
                gload16(xlp + xoff, (char*)&xl_s[0][0] + ldso);
                gload16(whp + woff, (char*)&wh_s[0][0] + ldso);
                gload16(wlp + woff, (char*)&wl_s[0][0] + ldso);
            }
            __syncthreads();     // staging complete

            bf16x8 ah[4], al[4], bh[4], bl[4];
            #pragma unroll
            for (int rt = 0; rt < 4; ++rt) {
                int off = (wr*64 + rt*16 + l15) * (BK*2) + sl*16;
                ah[rt] = *(const bf16x8*)((const char*)&xh_s[0][0] + off);
                al[rt] = *(const bf16x8*)((const char*)&xl_s[0][0] + off);
            }
            #pragma unroll
            for (int ct = 0; ct < 4; ++ct) {
                int off = (wc*64 + ct*16 + l15) * (BK*2) + sl*16;
                bh[ct] = *(const bf16x8*)((const char*)&wh_s[0][0] + off);
                bl[ct] = *(const bf16x8*)((const char*)&wl_s[0][0] + off);
            }
            #pragma unroll
            for (int rt = 0; rt < 4; ++rt)
                #pragma unroll
                for (int ct = 0; ct < 4; ++ct) {
                    acc[rt][ct] = __builtin_amdgcn_mfma_f32_16x16x32_bf16(al[rt], bh[ct], acc[rt][ct], 0, 0, 0);
                    acc[rt][ct] = __builtin_amdgcn_mfma_f32_16x16x32_bf16(ah[rt], bl[ct], acc[rt][ct], 0, 0, 0);
                    acc[rt][ct] = __builtin_amdgcn_mfma_f32_16x16x32_bf16(ah[rt], bh[ct], acc[rt][ct], 0, 0, 0);
                }
        }

        // score tile: dist = (x2 - 2*xw) + w2, C layout col=lane&15, row=quad*4+reg
        // x2 loaded here (L1-hot after tile 0) instead of a persistent 16-reg array:
        // frees 16 regs so the unified live set fits the 3-waves/SIMD bucket (<=170).
        f32x4 x2v[4];
        #pragma unroll
        for (int rt = 0; rt < 4; ++rt)
            x2v[rt] = *(const f32x4*)(x2 + gm + wr*64 + rt*16 + quad*4);
        float w2c[4];
        int   cidx[4];
        #pragma unroll
        for (int ct = 0; ct < 4; ++ct) {
            cidx[ct] = nb + wc*64 + ct*16 + l15;
            w2c[ct]  = w2[cidx[ct]];
        }
        #pragma unroll
        for (int rt = 0; rt < 4; ++rt)
            #pragma unroll
            for (int ct = 0; ct < 4; ++ct) {
                #pragma unroll
                for (int reg = 0; reg < 4; ++reg) {
                    float d = (x2v[rt][reg] - 2.0f * acc[rt][ct][reg]) + w2c[ct];
                    int r16 = rt*4 + reg;
                    if (d < minv[r16]) { minv[r16] = d; mini[r16] = cidx[ct]; }
                }
            }
    }

    // reduce across the 16 lanes (same rows, different cols); tie-break lower index
    #pragma unroll
    for (int r16 = 0; r16 < 16; ++r16) {
        float d  = minv[r16];
        int   ix = mini[r16];
        #pragma unroll
        for (int off = 1; off < 16; off <<= 1) {
            float od = __shfl_xor(d, off);
            int   oi = __shfl_xor(ix, off);
            if (od < d || (od == d && oi < ix)) { d = od; ix = oi; }
        }
        if (l15 == 0) {
            int row_local = wr*64 + (r16 >> 2)*16 + quad*4 + (r16 & 3);
            red_d[row_local][wc] = d;
            red_i[row_local][wc] = ix;
        }
    }
    __syncthreads();
    // combine the two col-halves, write per-split partials
    if (tid < BM) {
        float d0 = red_d[tid][0], d1 = red_d[tid][1];
        int   i0 = red_i[tid][0], i1 = red_i[tid][1];
        float d; int ix;
        if (d1 < d0 || (d1 == d0 && i1 < i0)) { d = d1; ix = i1; } else { d = d0; ix = i0; }
        pminv[(size_t)(gm + tid) * NSPLIT + split] = d;
        pmini[(size_t)(gm + tid) * NSPLIT + split] = ix;
    }
}

// ---------------- epilogue: reduce NSPLIT partials in-wave, then z_q/z/x/indices ----------------
__global__ void vq_gather(const float* __restrict__ x, const float* __restrict__ cb,
                          const float* __restrict__ pminv, const int* __restrict__ pmini,
                          float* __restrict__ out) {
    int t = blockIdx.x * blockDim.x + threadIdx.x;   // float4 units
    int m = t >> 6;
    int q = t & 63;        // == lane: one wave handles exactly one row

    // NSPLIT-way split reduce, replicated across lanes via xor shuffles
    float d  = pminv[(size_t)m * NSPLIT + (q & (NSPLIT-1))];
    int   ix = pmini[(size_t)m * NSPLIT + (q & (NSPLIT-1))];
    #pragma unroll
    for (int off = 1; off < NSPLIT; off <<= 1) {
        float od = __shfl_xor(d, off);
        int   oi = __shfl_xor(ix, off);
        if (od < d || (od == d && oi < ix)) { d = od; ix = oi; }
    }

    float4 xv = ((const float4*)x)[t];
    float4 zv = ((const float4*)cb)[(size_t)ix * 64 + q];
    float4 zq;
    zq.x = xv.x + (zv.x - xv.x);
    zq.y = xv.y + (zv.y - xv.y);
    zq.z = xv.z + (zv.z - xv.z);
    zq.w = xv.w + (zv.w - xv.w);
    float4* o = (float4*)out;
    const int ELEM4 = M_TOK * 64;
    o[t]           = zq;     // z_q
    o[t + ELEM4]   = zv;     // z
    o[t + 2*ELEM4] = xv;     // x
    if (q == 0) out[(size_t)3 * M_TOK * K_DIM + m] = (float)ix;
}

// ---------------- launcher ----------------
extern "C" void kernel_launch(void* const* d_in, const int* in_sizes, int n_in,
                              void* d_out, int out_size, void* d_ws, size_t ws_size,
                              hipStream_t stream) {
    const float* x  = (const float*)d_in[0];   // 16384 x 256
    const float* cb = (const float*)d_in[1];   // 8192 x 256
    float* out = (float*)d_out;

    // workspace layout
    char* p = (char*)d_ws;
    unsigned short* xh = (unsigned short*)p;  p += (size_t)M_TOK  * K_DIM * 2;  // 8 MB
    unsigned short* xl = (unsigned short*)p;  p += (size_t)M_TOK  * K_DIM * 2;  // 8 MB
    unsigned short* wh = (unsigned short*)p;  p += (size_t)N_CODE * K_DIM * 2;  // 4 MB
    unsigned short* wl = (unsigned short*)p;  p += (size_t)N_CODE * K_DIM * 2;  // 4 MB
    float* x2    = (float*)p;  p += (size_t)M_TOK * 4;
    float* w2    = (float*)p;  p += (size_t)N_CODE * 4;
    float* pminv = (float*)p;  p += (size_t)M_TOK * NSPLIT * 4;
    int*   pmini = (int*)p;    p += (size_t)M_TOK * NSPLIT * 4;

    // prep: one wave per row, 24576 rows
    {
        int waves = M_TOK + N_CODE;
        vq_prep<<<(waves * 64 + 255) / 256, 256, 0, stream>>>(x, cb, xh, xl, wh, wl, x2, w2);
    }
    // main fused MFMA GEMM + argmin (BK=32, 3 blocks/CU, 2048 short blocks)
    {
        dim3 grid(NSPLIT, M_TOK / BM);   // 16 x 128 = 2048 blocks
        vq_main_mfma<<<grid, 256, 0, stream>>>(xh, xl, wh, wl, x2, w2, pminv, pmini);
    }
    // epilogue (split-reduce fused in)
    {
        int t = M_TOK * (K_DIM / 4);     // 1048576 float4 threads
        vq_gather<<<t / 256, 256, 0, stream>>>(x, cb, pminv, pmini, out);
    }
}

// Round 8
// 325.790 us; speedup vs baseline: 1.2389x; 1.2389x over previous
//
#include <hip/hip_runtime.h>
#include <hip/hip_bf16.h>
#include <cstddef>
#include <cstdint>

// ---------------- problem constants ----------------
#define M_TOK   16384      // 32*512 tokens
#define N_CODE  8192       // NUM_LATENTS
#define K_DIM   256        // LATENT_DIM
#define NSPLIT  4
#define BM      128
#define BN      128
#define BK      64         // 128B LDS rows = 32 banks; 8x16B chunks XOR-swizzled

// R13: R5/R11 champion skeleton with the MFMA shape switched 16x16x32 -> 32x32x16.
// Rationale (7-round synthesis): serialization model MFMA 3725 + LDSread 3072 +
// LDSwrite 1024 + drain ~= 7540 cyc/CU/kc matches measurement; occupancy is
// reg-capped at 2 blocks/CU (R10/R12 spills), intra-block overlap unreachable at
// HIP level (R6/R7/R8), HBM not binding (34%). Only untouched lever: matrix RATE.
// 32x32x16 bf16 = 2495 TF ubench vs 2075 for 16x16x32 (m119/m06) -> matrix time
// 3725 -> ~3100 cyc/step. Same wave tile (64x64 = 2x2 of 32x32), same LDS volume,
// same staging/swizzle. A-frag layout: row = lane&31, k = (lane>>5)*8 + j (same
// family as the verified 16x16 mapping); C/D: col = lane&31,
// row = (reg&3) + 8*(reg>>2) + 4*(lane>>5)  [guide m74/m101, HW-verified].
// RISK: accumulation grouping changes (32-wide vs 16-wide dots) -> last-ulp score
// perturbation could flip a near-tie argmin. Watch absmax. Watch WRITE_SIZE for
// spill (minv/mini grow to 32 entries).

typedef short bf16x8 __attribute__((ext_vector_type(8)));   // 8 bf16 = 4 VGPRs
typedef float f32x4  __attribute__((ext_vector_type(4)));
typedef float f32x16 __attribute__((ext_vector_type(16)));  // 32x32 accumulator

__device__ __forceinline__ unsigned short f2bf_rne(float f) {
    unsigned u = __float_as_uint(f);
    unsigned r = u + 0x7FFFu + ((u >> 16) & 1u);
    return (unsigned short)(r >> 16);
}
__device__ __forceinline__ float bf2f(unsigned short h) {
    union { unsigned u; float f; } c; c.u = ((unsigned)h) << 16; return c.f;
}

__device__ __forceinline__ void gload16(const void* g, void* l) {
    __builtin_amdgcn_global_load_lds(
        (const __attribute__((address_space(1))) void*)g,
        (__attribute__((address_space(3))) void*)l, 16, 0, 0);
}

// ---------------- prep: bf16 hi/lo split + fp32 norms ----------------
__global__ void vq_prep(const float* __restrict__ x, const float* __restrict__ cb,
                        unsigned short* __restrict__ xh, unsigned short* __restrict__ xl,
                        unsigned short* __restrict__ wh, unsigned short* __restrict__ wl,
                        float* __restrict__ x2, float* __restrict__ w2) {
    int gt   = blockIdx.x * blockDim.x + threadIdx.x;
    int row  = gt >> 6;
    int lane = gt & 63;
    if (row >= M_TOK + N_CODE) return;
    const float* src; unsigned short *dh, *dl; float* dn;
    if (row < M_TOK) {
        src = x + (size_t)row * K_DIM;
        dh = xh + (size_t)row * K_DIM; dl = xl + (size_t)row * K_DIM; dn = x2 + row;
    } else {
        int r = row - M_TOK;
        src = cb + (size_t)r * K_DIM;
        dh = wh + (size_t)r * K_DIM; dl = wl + (size_t)r * K_DIM; dn = w2 + r;
    }
    float4 v = ((const float4*)src)[lane];
    unsigned short h0 = f2bf_rne(v.x), h1 = f2bf_rne(v.y);
    unsigned short h2 = f2bf_rne(v.z), h3 = f2bf_rne(v.w);
    unsigned short l0 = f2bf_rne(v.x - bf2f(h0)), l1 = f2bf_rne(v.y - bf2f(h1));
    unsigned short l2 = f2bf_rne(v.z - bf2f(h2)), l3 = f2bf_rne(v.w - bf2f(h3));
    ushort4 hv; hv.x = h0; hv.y = h1; hv.z = h2; hv.w = h3;
    ushort4 lv; lv.x = l0; lv.y = l1; lv.z = l2; lv.w = l3;
    ((ushort4*)dh)[lane] = hv;
    ((ushort4*)dl)[lane] = lv;
    float s = v.x*v.x + v.y*v.y + v.z*v.z + v.w*v.w;
    #pragma unroll
    for (int off = 32; off > 0; off >>= 1) s += __shfl_down(s, off);
    if (lane == 0) *dn = s;
}

// ---------------- main: 3-term bf16 32x32x16 MFMA GEMM fused with argmin ----------------
__global__ __launch_bounds__(256, 2)
void vq_main_mfma(const unsigned short* __restrict__ xh, const unsigned short* __restrict__ xl,
                  const unsigned short* __restrict__ wh, const unsigned short* __restrict__ wl,
                  const float* __restrict__ x2, const float* __restrict__ w2,
                  float* __restrict__ pminv, int* __restrict__ pmini) {
    // [128 rows][64 bf16] = 128 B row = exactly 32 banks; 16 KB each
    __shared__ unsigned short xh_s[BM][BK];
    __shared__ unsigned short xl_s[BM][BK];
    __shared__ unsigned short wh_s[BN][BK];
    __shared__ unsigned short wl_s[BN][BK];
    __shared__ float red_d[BM][2];
    __shared__ int   red_i[BM][2];

    const int split = blockIdx.x;            // 0..NSPLIT-1
    const int mtile = blockIdx.y;            // 0..127
    const int gm    = mtile * BM;
    const int tid   = threadIdx.x;
    const int w     = tid >> 6;              // wave 0..3
    const int lane  = tid & 63;
    const int wr    = w >> 1;                // row half (0/1)
    const int wc    = w & 1;                 // col half (0/1)
    const int l31   = lane & 31;             // 32x32 row/col within tile
    const int hi    = lane >> 5;             // k-chunk select (0/1)

    // staging addressing (IDENTICAL to R5/R11): wave w stages rows [w*32, w*32+32).
    // round i: lane covers row w*32 + i*8 + (lane>>3), swizzled global chunk
    // g = (lane&7) ^ (lane>>3); LDS slot s of row r holds global chunk s ^ (r&7).
    const int w32   = w * 32;
    const int srl   = lane >> 3;                       // 0..7
    const int sg    = (lane & 7) ^ srl;                // global 16B chunk this lane fetches

    float minv[32];
    int   mini[32];
    #pragma unroll
    for (int i = 0; i < 32; ++i) { minv[i] = 3.4e38f; mini[i] = 0; }

    const char* xhp = (const char*)xh;
    const char* xlp = (const char*)xl;
    const char* whp = (const char*)wh;
    const char* wlp = (const char*)wl;

    const int tiles = (N_CODE / NSPLIT) / BN;    // 16
    for (int tile = 0; tile < tiles; ++tile) {
        const int nb = split * (N_CODE / NSPLIT) + tile * BN;

        f32x16 acc[2][2];
        #pragma unroll
        for (int rt = 0; rt < 2; ++rt)
            #pragma unroll
            for (int ct = 0; ct < 2; ++ct)
                #pragma unroll
                for (int r = 0; r < 16; ++r)
                    acc[rt][ct][r] = 0.f;

        for (int kc = 0; kc < K_DIM / BK; ++kc) {    // 4
            __syncthreads();     // protect LDS from previous iteration's readers
            #pragma unroll
            for (int i = 0; i < 4; ++i) {
                int rowl = w32 + i * 8 + srl;        // tile row this lane fetches
                size_t xoff = (size_t)(gm + rowl) * (K_DIM*2) + kc*(BK*2) + sg*16;
                size_t woff = (size_t)(nb + rowl) * (K_DIM*2) + kc*(BK*2) + sg*16;
                unsigned ldso = (unsigned)w32 * (BK*2) + i * 1024;   // wave-uniform
                gload16(xhp + xoff, (char*)&xh_s[0][0] + ldso);
                gload16(xlp + xoff, (char*)&xl_s[0][0] + ldso);
                gload16(whp + woff, (char*)&wh_s[0][0] + ldso);
                gload16(wlp + woff, (char*)&wl_s[0][0] + ldso);
            }
            __syncthreads();     // staging complete

            #pragma unroll
            for (int ks = 0; ks < 4; ++ks) {         // four 16-K steps within BK=64
                // lane reads 16B = 8 bf16 at k-chunk (ks*2 + hi); slot = chunk ^ (row&7);
                // row&7 == lane&7 (64/32 offsets are multiples of 8). Consecutive-8-lane
                // groups cover 8 distinct slots -> conflict-free (R5-validated pattern).
                const int sl = ((ks << 1) + hi) ^ (lane & 7);
                bf16x8 ah[2], al[2], bh[2], bl[2];
                #pragma unroll
                for (int rt = 0; rt < 2; ++rt) {
                    int off = (wr*64 + rt*32 + l31) * (BK*2) + sl*16;
                    ah[rt] = *(const bf16x8*)((const char*)&xh_s[0][0] + off);
                    al[rt] = *(const bf16x8*)((const char*)&xl_s[0][0] + off);
                }
                #pragma unroll
                for (int ct = 0; ct < 2; ++ct) {
                    int off = (wc*64 + ct*32 + l31) * (BK*2) + sl*16;
                    bh[ct] = *(const bf16x8*)((const char*)&wh_s[0][0] + off);
                    bl[ct] = *(const bf16x8*)((const char*)&wl_s[0][0] + off);
                }
                #pragma unroll
                for (int rt = 0; rt < 2; ++rt)
                    #pragma unroll
                    for (int ct = 0; ct < 2; ++ct) {
                        acc[rt][ct] = __builtin_amdgcn_mfma_f32_32x32x16_bf16(al[rt], bh[ct], acc[rt][ct], 0, 0, 0);
                        acc[rt][ct] = __builtin_amdgcn_mfma_f32_32x32x16_bf16(ah[rt], bl[ct], acc[rt][ct], 0, 0, 0);
                        acc[rt][ct] = __builtin_amdgcn_mfma_f32_32x32x16_bf16(ah[rt], bh[ct], acc[rt][ct], 0, 0, 0);
                    }
            }
        }

        // score tile: dist = (x2 - 2*xw) + w2
        // C layout (32x32): col = lane&31, row = (reg&3) + 8*(reg>>2) + 4*(lane>>5)
        f32x4 x2v[2][4];
        #pragma unroll
        for (int rt = 0; rt < 2; ++rt)
            #pragma unroll
            for (int rq = 0; rq < 4; ++rq)
                x2v[rt][rq] = *(const f32x4*)(x2 + gm + wr*64 + rt*32 + 4*hi + rq*8);
        float w2c[2];
        int   cidx[2];
        #pragma unroll
        for (int ct = 0; ct < 2; ++ct) {
            cidx[ct] = nb + wc*64 + ct*32 + l31;
            w2c[ct]  = w2[cidx[ct]];
        }
        #pragma unroll
        for (int rt = 0; rt < 2; ++rt)
            #pragma unroll
            for (int ct = 0; ct < 2; ++ct) {
                #pragma unroll
                for (int r = 0; r < 16; ++r) {
                    float d = (x2v[rt][r >> 2][r & 3] - 2.0f * acc[rt][ct][r]) + w2c[ct];
                    int s = rt*16 + r;
                    if (d < minv[s]) { minv[s] = d; mini[s] = cidx[ct]; }
                }
            }
    }

    // reduce across the 32 cols (lanes sharing hi hold the same row); tie-break lower idx
    #pragma unroll
    for (int s = 0; s < 32; ++s) {
        float d  = minv[s];
        int   ix = mini[s];
        #pragma unroll
        for (int off = 1; off < 32; off <<= 1) {     // xor<=16 stays within the 32-half
            float od = __shfl_xor(d, off);
            int   oi = __shfl_xor(ix, off);
            if (od < d || (od == d && oi < ix)) { d = od; ix = oi; }
        }
        if (l31 == 0) {                              // lanes 0 (hi=0) and 32 (hi=1)
            int rt = s >> 4, r = s & 15;
            int row_local = wr*64 + rt*32 + 4*hi + (r & 3) + 8*(r >> 2);
            red_d[row_local][wc] = d;
            red_i[row_local][wc] = ix;
        }
    }
    __syncthreads();
    // combine the two col-halves, write per-split partials
    if (tid < BM) {
        float d0 = red_d[tid][0], d1 = red_d[tid][1];
        int   i0 = red_i[tid][0], i1 = red_i[tid][1];
        float d; int ix;
        if (d1 < d0 || (d1 == d0 && i1 < i0)) { d = d1; ix = i1; } else { d = d0; ix = i0; }
        pminv[(size_t)(gm + tid) * NSPLIT + split] = d;
        pmini[(size_t)(gm + tid) * NSPLIT + split] = ix;
    }
}

// ---------------- epilogue: reduce NSPLIT partials in-wave, then z_q/z/x/indices ----------------
__global__ void vq_gather(const float* __restrict__ x, const float* __restrict__ cb,
                          const float* __restrict__ pminv, const int* __restrict__ pmini,
                          float* __restrict__ out) {
    int t = blockIdx.x * blockDim.x + threadIdx.x;   // float4 units
    int m = t >> 6;
    int q = t & 63;        // == lane: one wave handles exactly one row

    // NSPLIT-way split reduce, replicated across lanes via xor shuffles
    float d  = pminv[(size_t)m * NSPLIT + (q & (NSPLIT-1))];
    int   ix = pmini[(size_t)m * NSPLIT + (q & (NSPLIT-1))];
    #pragma unroll
    for (int off = 1; off < NSPLIT; off <<= 1) {
        float od = __shfl_xor(d, off);
        int   oi = __shfl_xor(ix, off);
        if (od < d || (od == d && oi < ix)) { d = od; ix = oi; }
    }

    float4 xv = ((const float4*)x)[t];
    float4 zv = ((const float4*)cb)[(size_t)ix * 64 + q];
    float4 zq;
    zq.x = xv.x + (zv.x - xv.x);
    zq.y = xv.y + (zv.y - xv.y);
    zq.z = xv.z + (zv.z - xv.z);
    zq.w = xv.w + (zv.w - xv.w);
    float4* o = (float4*)out;
    const int ELEM4 = M_TOK * 64;
    o[t]           = zq;     // z_q
    o[t + ELEM4]   = zv;     // z
    o[t + 2*ELEM4] = xv;     // x
    if (q == 0) out[(size_t)3 * M_TOK * K_DIM + m] = (float)ix;
}

// ---------------- launcher ----------------
extern "C" void kernel_launch(void* const* d_in, const int* in_sizes, int n_in,
                              void* d_out, int out_size, void* d_ws, size_t ws_size,
                              hipStream_t stream) {
    const float* x  = (const float*)d_in[0];   // 16384 x 256
    const float* cb = (const float*)d_in[1];   // 8192 x 256
    float* out = (float*)d_out;

    // workspace layout
    char* p = (char*)d_ws;
    unsigned short* xh = (unsigned short*)p;  p += (size_t)M_TOK  * K_DIM * 2;  // 8 MB
    unsigned short* xl = (unsigned short*)p;  p += (size_t)M_TOK  * K_DIM * 2;  // 8 MB
    unsigned short* wh = (unsigned short*)p;  p += (size_t)N_CODE * K_DIM * 2;  // 4 MB
    unsigned short* wl = (unsigned short*)p;  p += (size_t)N_CODE * K_DIM * 2;  // 4 MB
    float* x2    = (float*)p;  p += (size_t)M_TOK * 4;
    float* w2    = (float*)p;  p += (size_t)N_CODE * 4;
    float* pminv = (float*)p;  p += (size_t)M_TOK * NSPLIT * 4;
    int*   pmini = (int*)p;    p += (size_t)M_TOK * NSPLIT * 4;

    // prep: one wave per row, 24576 rows
    {
        int waves = M_TOK + N_CODE;
        vq_prep<<<(waves * 64 + 255) / 256, 256, 0, stream>>>(x, cb, xh, xl, wh, wl, x2, w2);
    }
    // main fused MFMA GEMM + argmin (32x32x16 shape)
    {
        dim3 grid(NSPLIT, M_TOK / BM);   // 4 x 128 = 512 blocks
        vq_main_mfma<<<grid, 256, 0, stream>>>(xh, xl, wh, wl, x2, w2, pminv, pmini);
    }
    // epilogue (split-reduce fused in)
    {
        int t = M_TOK * (K_DIM / 4);     // 1048576 float4 threads
        vq_gather<<<t / 256, 256, 0, stream>>>(x, cb, pminv, pmini, out);
    }
}

// Round 9
// 293.966 us; speedup vs baseline: 1.3731x; 1.1083x over previous
//
#include <hip/hip_runtime.h>
#include <hip/hip_bf16.h>
#include <cstddef>
#include <cstdint>

// ---------------- problem constants ----------------
#define M_TOK   16384      // 32*512 tokens
#define N_CODE  8192       // NUM_LATENTS
#define K_DIM   256        // LATENT_DIM
#define NSPLIT  4
#define BM      128
#define BN      256        // R14: asymmetric tile; wave owns 64x128 (4rt x 8ct)
#define BK      32
#define KSTEPS  (K_DIM / BK)                 // 8
#define TILES   ((N_CODE / NSPLIT) / BN)     // 8

// R14 (9-round synthesis): serial model t = MFMA + LDSread + stage + barrier validated
// to ~5%. Closed levers: MFMA rate (R13: 32x32 -> 16.8M bank conflicts, mechanism
// underivable), occupancy (R10/R12: reg-bucket spills), intra-block overlap (R6/R7/R8).
// Remaining lever: LDS READ COUNT. 64x128 wave tile: 24 b128 per 96 MFMA (0.25/MFMA)
// vs 64x64's 16 per 48 (0.33) -> -25% reads, -25% staged bytes, same MFMA total.
// Per-accumulator K-slice sequence identical (8 ascending 32-K slices, same
// al*bh/ah*bl/ah*bh triple) -> bit-exact scores vs R5/R11 champion.
// Spill control (3 prior deaths): acc=128 forces B-frags just-in-time in 4 pinned
// groups of 2 ct (sched_barrier(0) between groups caps B liveness at 16 regs).
// Live est: 128 acc + 32 A + 16 B + 32 min + ~25 misc = 233 < 256 bucket.
// Failure signature to watch: WRITE_SIZE >> 2 MB = spill -> revert champion.

typedef short bf16x8 __attribute__((ext_vector_type(8)));  // 8 bf16 = 4 VGPRs
typedef float f32x4  __attribute__((ext_vector_type(4)));

__device__ __forceinline__ unsigned short f2bf_rne(float f) {
    unsigned u = __float_as_uint(f);
    unsigned r = u + 0x7FFFu + ((u >> 16) & 1u);
    return (unsigned short)(r >> 16);
}
__device__ __forceinline__ float bf2f(unsigned short h) {
    union { unsigned u; float f; } c; c.u = ((unsigned)h) << 16; return c.f;
}

__device__ __forceinline__ void gload16(const void* g, void* l) {
    __builtin_amdgcn_global_load_lds(
        (const __attribute__((address_space(1))) void*)g,
        (__attribute__((address_space(3))) void*)l, 16, 0, 0);
}

// ---------------- prep: bf16 hi/lo split + fp32 norms ----------------
__global__ void vq_prep(const float* __restrict__ x, const float* __restrict__ cb,
                        unsigned short* __restrict__ xh, unsigned short* __restrict__ xl,
                        unsigned short* __restrict__ wh, unsigned short* __restrict__ wl,
                        float* __restrict__ x2, float* __restrict__ w2) {
    int gt   = blockIdx.x * blockDim.x + threadIdx.x;
    int row  = gt >> 6;
    int lane = gt & 63;
    if (row >= M_TOK + N_CODE) return;
    const float* src; unsigned short *dh, *dl; float* dn;
    if (row < M_TOK) {
        src = x + (size_t)row * K_DIM;
        dh = xh + (size_t)row * K_DIM; dl = xl + (size_t)row * K_DIM; dn = x2 + row;
    } else {
        int r = row - M_TOK;
        src = cb + (size_t)r * K_DIM;
        dh = wh + (size_t)r * K_DIM; dl = wl + (size_t)r * K_DIM; dn = w2 + r;
    }
    float4 v = ((const float4*)src)[lane];
    unsigned short h0 = f2bf_rne(v.x), h1 = f2bf_rne(v.y);
    unsigned short h2 = f2bf_rne(v.z), h3 = f2bf_rne(v.w);
    unsigned short l0 = f2bf_rne(v.x - bf2f(h0)), l1 = f2bf_rne(v.y - bf2f(h1));
    unsigned short l2 = f2bf_rne(v.z - bf2f(h2)), l3 = f2bf_rne(v.w - bf2f(h3));
    ushort4 hv; hv.x = h0; hv.y = h1; hv.z = h2; hv.w = h3;
    ushort4 lv; lv.x = l0; lv.y = l1; lv.z = l2; lv.w = l3;
    ((ushort4*)dh)[lane] = hv;
    ((ushort4*)dl)[lane] = lv;
    float s = v.x*v.x + v.y*v.y + v.z*v.z + v.w*v.w;
    #pragma unroll
    for (int off = 32; off > 0; off >>= 1) s += __shfl_down(s, off);
    if (lane == 0) *dn = s;
}

// ---------------- main: 3-term bf16 MFMA GEMM (64x128 wave tile) + argmin ----------------
// Swizzle (R10/R12-proven: 0 conflicts, bit-exact): LDS slot s of row r holds global
// chunk s ^ ((r>>1)&3); staging lane fetches chunk (lane&3)^((lane>>3)&3); read slot
// quad ^ ((l15>>1)&3). Row stride 64 B; all row offsets (wr*64, wc*128, rt/ct*16,
// w*32/64, i*16) are multiples of 16, so (row>>1)&3 == (l15>>1)&3 everywhere.
__global__ __launch_bounds__(256, 2)
void vq_main_mfma(const unsigned short* __restrict__ xh, const unsigned short* __restrict__ xl,
                  const unsigned short* __restrict__ wh, const unsigned short* __restrict__ wl,
                  const float* __restrict__ x2, const float* __restrict__ w2,
                  float* __restrict__ pminv, int* __restrict__ pmini) {
    // x: [128][32] = 8 KB/plane; w: [256][32] = 16 KB/plane; total 48 KB
    __shared__ unsigned short xh_s[BM][BK];
    __shared__ unsigned short xl_s[BM][BK];
    __shared__ unsigned short wh_s[BN][BK];
    __shared__ unsigned short wl_s[BN][BK];
    __shared__ float red_d[BM][2];
    __shared__ int   red_i[BM][2];

    const int split = blockIdx.x;            // 0..3
    const int mtile = blockIdx.y;            // 0..127
    const int gm    = mtile * BM;
    const int tid   = threadIdx.x;
    const int w     = tid >> 6;              // wave 0..3
    const int lane  = tid & 63;
    const int wr    = w >> 1;                // row half (0/1): rows wr*64..+64
    const int wc    = w & 1;                 // col half (0/1): cols wc*128..+128
    const int quad  = lane >> 4;             // 0..3
    const int l15   = lane & 15;

    // staging constants
    const int w32   = w * 32;                          // x rows per wave
    const int w64   = w * 64;                          // w rows per wave
    const int srow4 = lane >> 2;                       // 0..15
    const int sg    = (lane & 3) ^ ((lane >> 3) & 3);  // pre-swizzled global chunk

    float minv[16];
    int   mini[16];
    #pragma unroll
    for (int i = 0; i < 16; ++i) { minv[i] = 3.4e38f; mini[i] = 0; }

    const char* xhp = (const char*)xh;
    const char* xlp = (const char*)xl;
    const char* whp = (const char*)wh;
    const char* wlp = (const char*)wl;

    const int sl = quad ^ ((l15 >> 1) & 3);    // swizzled read slot (0..3)

    for (int tile = 0; tile < TILES; ++tile) {
        const int nb = split * (N_CODE / NSPLIT) + tile * BN;

        f32x4 acc[4][8];
        #pragma unroll
        for (int rt = 0; rt < 4; ++rt)
            #pragma unroll
            for (int ct = 0; ct < 8; ++ct)
                acc[rt][ct] = (f32x4){0.f, 0.f, 0.f, 0.f};

        for (int kc = 0; kc < KSTEPS; ++kc) {
            __syncthreads();     // protect LDS from previous iteration's readers
            // stage x: wave w covers rows [w*32, w*32+32), 2 instrs of 16 rows/plane
            #pragma unroll
            for (int i = 0; i < 2; ++i) {
                int rowl = w32 + i * 16 + srow4;
                size_t xoff = (size_t)(gm + rowl) * (K_DIM*2) + (size_t)kc*(BK*2) + (size_t)sg*16;
                unsigned ldso = (unsigned)w32 * (BK*2) + i * 1024;   // wave-uniform
                gload16(xhp + xoff, (char*)&xh_s[0][0] + ldso);
                gload16(xlp + xoff, (char*)&xl_s[0][0] + ldso);
            }
            // stage w: wave w covers rows [w*64, w*64+64), 4 instrs of 16 rows/plane
            #pragma unroll
            for (int i = 0; i < 4; ++i) {
                int rowl = w64 + i * 16 + srow4;
                size_t woff = (size_t)(nb + rowl) * (K_DIM*2) + (size_t)kc*(BK*2) + (size_t)sg*16;
                unsigned ldso = (unsigned)w64 * (BK*2) + i * 1024;   // wave-uniform
                gload16(whp + woff, (char*)&wh_s[0][0] + ldso);
                gload16(wlp + woff, (char*)&wl_s[0][0] + ldso);
            }
            __syncthreads();     // staging complete

            // A fragments: 8 reads, live across all ct groups (32 regs)
            bf16x8 ah[4], al[4];
            #pragma unroll
            for (int rt = 0; rt < 4; ++rt) {
                int off = (wr*64 + rt*16 + l15) * (BK*2) + sl*16;
                ah[rt] = *(const bf16x8*)((const char*)&xh_s[0][0] + off);
                al[rt] = *(const bf16x8*)((const char*)&xl_s[0][0] + off);
            }
            // B fragments just-in-time in 4 pinned groups of 2 ct (caps B live at 16)
            #pragma unroll
            for (int g = 0; g < 4; ++g) {
                bf16x8 bh[2], bl[2];
                #pragma unroll
                for (int c = 0; c < 2; ++c) {
                    int ct  = g*2 + c;
                    int off = (wc*128 + ct*16 + l15) * (BK*2) + sl*16;
                    bh[c] = *(const bf16x8*)((const char*)&wh_s[0][0] + off);
                    bl[c] = *(const bf16x8*)((const char*)&wl_s[0][0] + off);
                }
                #pragma unroll
                for (int rt = 0; rt < 4; ++rt)
                    #pragma unroll
                    for (int c = 0; c < 2; ++c) {
                        acc[rt][g*2+c] = __builtin_amdgcn_mfma_f32_16x16x32_bf16(al[rt], bh[c], acc[rt][g*2+c], 0, 0, 0);
                        acc[rt][g*2+c] = __builtin_amdgcn_mfma_f32_16x16x32_bf16(ah[rt], bl[c], acc[rt][g*2+c], 0, 0, 0);
                        acc[rt][g*2+c] = __builtin_amdgcn_mfma_f32_16x16x32_bf16(ah[rt], bh[c], acc[rt][g*2+c], 0, 0, 0);
                    }
                __builtin_amdgcn_sched_barrier(0);   // pin: stop hoisting next group's B reads
            }
        }

        // score tile: dist = (x2 - 2*xw) + w2, C layout col=lane&15, row=quad*4+reg.
        // Visit order ct ascending -> first-seen min keeps lowest index (same as R5).
        f32x4 x2v[4];
        #pragma unroll
        for (int rt = 0; rt < 4; ++rt)
            x2v[rt] = *(const f32x4*)(x2 + gm + wr*64 + rt*16 + quad*4);
        #pragma unroll
        for (int ct = 0; ct < 8; ++ct) {
            int   cidx = nb + wc*128 + ct*16 + l15;
            float w2c  = w2[cidx];
            #pragma unroll
            for (int rt = 0; rt < 4; ++rt)
                #pragma unroll
                for (int reg = 0; reg < 4; ++reg) {
                    float d = (x2v[rt][reg] - 2.0f * acc[rt][ct][reg]) + w2c;
                    int r16 = rt*4 + reg;
                    if (d < minv[r16]) { minv[r16] = d; mini[r16] = cidx; }
                }
        }
    }

    // reduce across the 16 lanes (same rows, different cols); tie-break lower index
    #pragma unroll
    for (int r16 = 0; r16 < 16; ++r16) {
        float d  = minv[r16];
        int   ix = mini[r16];
        #pragma unroll
        for (int off = 1; off < 16; off <<= 1) {
            float od = __shfl_xor(d, off);
            int   oi = __shfl_xor(ix, off);
            if (od < d || (od == d && oi < ix)) { d = od; ix = oi; }
        }
        if (l15 == 0) {
            int row_local = wr*64 + (r16 >> 2)*16 + quad*4 + (r16 & 3);
            red_d[row_local][wc] = d;
            red_i[row_local][wc] = ix;
        }
    }
    __syncthreads();
    // combine the two col-halves, write per-split partials
    if (tid < BM) {
        float d0 = red_d[tid][0], d1 = red_d[tid][1];
        int   i0 = red_i[tid][0], i1 = red_i[tid][1];
        float d; int ix;
        if (d1 < d0 || (d1 == d0 && i1 < i0)) { d = d1; ix = i1; } else { d = d0; ix = i0; }
        pminv[(size_t)(gm + tid) * NSPLIT + split] = d;
        pmini[(size_t)(gm + tid) * NSPLIT + split] = ix;
    }
}

// ---------------- epilogue: reduce NSPLIT partials in-wave, then z_q/z/x/indices ----------------
__global__ void vq_gather(const float* __restrict__ x, const float* __restrict__ cb,
                          const float* __restrict__ pminv, const int* __restrict__ pmini,
                          float* __restrict__ out) {
    int t = blockIdx.x * blockDim.x + threadIdx.x;   // float4 units
    int m = t >> 6;
    int q = t & 63;        // == lane: one wave handles exactly one row

    // NSPLIT-way split reduce, replicated across lanes via xor shuffles
    float d  = pminv[(size_t)m * NSPLIT + (q & (NSPLIT-1))];
    int   ix = pmini[(size_t)m * NSPLIT + (q & (NSPLIT-1))];
    #pragma unroll
    for (int off = 1; off < NSPLIT; off <<= 1) {
        float od = __shfl_xor(d, off);
        int   oi = __shfl_xor(ix, off);
        if (od < d || (od == d && oi < ix)) { d = od; ix = oi; }
    }

    float4 xv = ((const float4*)x)[t];
    float4 zv = ((const float4*)cb)[(size_t)ix * 64 + q];
    float4 zq;
    zq.x = xv.x + (zv.x - xv.x);
    zq.y = xv.y + (zv.y - xv.y);
    zq.z = xv.z + (zv.z - xv.z);
    zq.w = xv.w + (zv.w - xv.w);
    float4* o = (float4*)out;
    const int ELEM4 = M_TOK * 64;
    o[t]           = zq;     // z_q
    o[t + ELEM4]   = zv;     // z
    o[t + 2*ELEM4] = xv;     // x
    if (q == 0) out[(size_t)3 * M_TOK * K_DIM + m] = (float)ix;
}

// ---------------- launcher ----------------
extern "C" void kernel_launch(void* const* d_in, const int* in_sizes, int n_in,
                              void* d_out, int out_size, void* d_ws, size_t ws_size,
                              hipStream_t stream) {
    const float* x  = (const float*)d_in[0];   // 16384 x 256
    const float* cb = (const float*)d_in[1];   // 8192 x 256
    float* out = (float*)d_out;

    // workspace layout
    char* p = (char*)d_ws;
    unsigned short* xh = (unsigned short*)p;  p += (size_t)M_TOK  * K_DIM * 2;  // 8 MB
    unsigned short* xl = (unsigned short*)p;  p += (size_t)M_TOK  * K_DIM * 2;  // 8 MB
    unsigned short* wh = (unsigned short*)p;  p += (size_t)N_CODE * K_DIM * 2;  // 4 MB
    unsigned short* wl = (unsigned short*)p;  p += (size_t)N_CODE * K_DIM * 2;  // 4 MB
    float* x2    = (float*)p;  p += (size_t)M_TOK * 4;
    float* w2    = (float*)p;  p += (size_t)N_CODE * 4;
    float* pminv = (float*)p;  p += (size_t)M_TOK * NSPLIT * 4;
    int*   pmini = (int*)p;    p += (size_t)M_TOK * NSPLIT * 4;

    // prep: one wave per row, 24576 rows
    {
        int waves = M_TOK + N_CODE;
        vq_prep<<<(waves * 64 + 255) / 256, 256, 0, stream>>>(x, cb, xh, xl, wh, wl, x2, w2);
    }
    // main fused MFMA GEMM + argmin (64x128 wave tile, BN=256)
    {
        dim3 grid(NSPLIT, M_TOK / BM);   // 4 x 128 = 512 blocks, 2 blocks/CU
        vq_main_mfma<<<grid, 256, 0, stream>>>(xh, xl, wh, wl, x2, w2, pminv, pmini);
    }
    // epilogue (split-reduce fused in)
    {
        int t = M_TOK * (K_DIM / 4);     // 1048576 float4 threads
        vq_gather<<<t / 256, 256, 0, stream>>>(x, cb, pminv, pmini, out);
    }
}